// Round 5
// baseline (98.779 us; speedup 1.0000x reference)
//
#include <hip/hip_runtime.h>
#include <stdint.h>

#define CIN 256
#define COUT 128
#define BATCH 8
#define HH 64
#define WW 64
#define XROW 66

// xb2: padded bf16 input, [B][66 rows][66 cols][4 cb][8 slot][8 ch], slot pre-swizzled by (col&7)
#define XB2_BYTES ((size_t)BATCH * XROW * XROW * CIN * 2)
// gw3: fused weights, [9 taps][2 py][4 cb][256 row=co*2+px][8 slot][8 ch], slot pre-swizzled by (row&7)
#define GW3_BYTES ((size_t)9 * 2 * 4 * 256 * 64 * 2)

typedef __bf16 bf16x8 __attribute__((ext_vector_type(8)));
typedef float f32x4 __attribute__((ext_vector_type(4)));

__device__ __forceinline__ unsigned short f2bf(float f) {
  unsigned int u = __float_as_uint(f);
  u += 0x7fffu + ((u >> 16) & 1u);
  return (unsigned short)(u >> 16);
}

__device__ __forceinline__ void gload_lds16(const void* g, void* l) {
  __builtin_amdgcn_global_load_lds(
      (__attribute__((address_space(1))) void*)(uintptr_t)g,
      (__attribute__((address_space(3))) void*)l, 16, 0, 0);
}

// ---------------- prep: x -> padded channel-last swizzled bf16 ----------------
__global__ __launch_bounds__(256) void prep_x(const float* __restrict__ x,
                                              unsigned short* __restrict__ xb2) {
  int b = blockIdx.x >> 6, iy = blockIdx.x & 63;
  __shared__ __align__(16) unsigned short lds[64][264];  // [ix][c]
  int t = threadIdx.x;
  int cq = t >> 6, ix = t & 63;
  for (int ci = 0; ci < 64; ++ci) {
    int c = ci * 4 + cq;
    float v = x[(((size_t)b * CIN + c) * HH + iy) * WW + ix];
    lds[ix][c] = f2bf(v);
  }
  __syncthreads();
  for (int it = 0; it < 8; ++it) {
    int u = it * 256 + t;  // 2048 units of 16B: 64 ix * 32 (cb,slot)
    int ixo = u >> 5;
    int q = u & 31, cb = q >> 3, slot = q & 7;
    int col = ixo + 1;  // padded col
    int c0 = cb * 64 + 8 * (slot ^ (col & 7));
    uint4 val = *reinterpret_cast<const uint4*>(&lds[ixo][c0]);
    size_t o = ((((size_t)(b * XROW + (iy + 1)) * XROW + col) * 4 + cb) * 8 + slot) * 8;
    *reinterpret_cast<uint4*>(&xb2[o]) = val;
  }
}

// ---------------- prep: fuse He-scale * conv3x3 (x) FIR into per-parity 3x3 taps ----------------
__global__ __launch_bounds__(256) void prep_w(const float* __restrict__ w,
                                              const float* __restrict__ f,
                                              unsigned short* __restrict__ gw3) {
  __shared__ float fs[16];
  int co = blockIdx.x;
  int c = threadIdx.x;
  if (c < 16) fs[c] = f[c];
  __syncthreads();
  float wl[3][3];
  const float he = 1.0f / 48.0f;  // 1/sqrt(256*9)
#pragma unroll
  for (int dy = 0; dy < 3; ++dy)
#pragma unroll
    for (int dx = 0; dx < 3; ++dx)
      wl[dy][dx] = w[((size_t)(co * CIN + c) * 3 + dy) * 3 + dx] * he;
  int cb = c >> 6, cl = c & 63;
  int ce = cl & 7;
  for (int d = 0; d < 3; ++d)
    for (int e = 0; e < 3; ++e)
      for (int py = 0; py < 2; ++py)
        for (int px = 0; px < 2; ++px) {
          int ty = 2 * d + 1 - py, tx = 2 * e + 1 - px;  // taps of 6x6 composite g
          float acc = 0.f;
          for (int dy = 0; dy < 3; ++dy) {
            int a = ty - dy;
            if (a < 0 || a > 3) continue;
            for (int dx = 0; dx < 3; ++dx) {
              int bb = tx - dx;
              if (bb < 0 || bb > 3) continue;
              acc += wl[dy][dx] * fs[a * 4 + bb];
            }
          }
          int row = co * 2 + px;
          int slot = (cl >> 3) ^ (row & 7);
          size_t o = ((((size_t)(d * 3 + e) * 2 + py) * 4 + cb) * 256 + row) * 64 + slot * 8 + ce;
          gw3[o] = f2bf(acc);
        }
}

// ---------------- main: implicit-GEMM polyphase conv, 256x256 tile, 8 waves ----------------
// M=256 (row = co*2+px), N=256 spatial (4 out sub-rows x 64 cols; wave wn owns sub-row wn),
// K=2304 in 36 steps of 64. Deep pipeline (T3+T4):
//   per step: stage A[s+1] (4 gload_lds) -> issue bfv[s+1] (8 asm global_load_dwordx4 to regs)
//   -> vmcnt(12) [retires bfv[s], issued a full step ago; A[s+1]+bfv[s+1] stay in flight]
//   -> 2 x {8 ds_read af + 32 MFMA} -> vmcnt(8) [A[s+1] landed; bfv[s+1] still in flight]
//   -> s_barrier.  ONE barrier/step; vmcnt never drains to 0 in the loop.
__global__ __launch_bounds__(512, 2) void conv_main(
    const unsigned short* __restrict__ xb2,
    const unsigned short* __restrict__ gw3,
    const float* __restrict__ bias,
    float* __restrict__ out) {
  __shared__ __align__(16) unsigned char smem[65536];
  unsigned short* at0 = (unsigned short*)smem;            // A buf 0: [256 row][8 slot][8 ch]
  unsigned short* at1 = (unsigned short*)(smem + 32768);  // A buf 1

  const int bid = blockIdx.x;
  const int py = bid >> 7;       // 0..1
  const int r0 = bid & 127;
  const int b = r0 >> 4;
  const int m0 = (r0 & 15) * 4;  // 4 output sub-rows per block

  const int t = threadIdx.x;
  const int lane = t & 63;
  const int wave = t >> 6;
  const int wm = wave >> 2;  // 0..1: M half
  const int wn = wave & 3;   // 0..3: output sub-row
  const int l15 = lane & 15, l4 = lane >> 4;

  f32x4 acc[8][4] = {};
  bf16x8 bfvA[4][2], bfvB[4][2];

  const unsigned long long xbu =
      (unsigned long long)xb2 + (size_t)((b * XROW + m0) * (XROW * 32)) * 16;

  // inline-asm global load: 16B to 4 VGPRs, 32-bit voffset + SGPR base (backend does
  // NOT auto-wait asm outputs; retirement is via the manual counted vmcnt below)
#define GLOAD(dst, voffexpr)                                               \
  do {                                                                     \
    int voff_ = (voffexpr);                                                \
    asm volatile("global_load_dwordx4 %0, %1, %2"                          \
                 : "=v"(dst)                                               \
                 : "v"(voff_), "s"(xbu)                                    \
                 : "memory");                                              \
  } while (0)

  // stage next A tile (4 x gload_lds, 32KB, linear dest, pre-swizzled source)
#define STAGE_A(buf, de_, cb_)                                                        \
  do {                                                                                \
    const char* g = (const char*)gw3 + ((((size_t)(de_)*2 + py) * 4 + (cb_)) << 15);  \
    int off = t * 16;                                                                 \
    gload_lds16(g + off, (char*)(buf) + off);                                         \
    gload_lds16(g + off + 8192, (char*)(buf) + off + 8192);                           \
    gload_lds16(g + off + 16384, (char*)(buf) + off + 16384);                         \
    gload_lds16(g + off + 24576, (char*)(buf) + off + 24576);                         \
  } while (0)

  // issue the 8 bfv loads for tap (d_,e_,cb_): j=0..3 cols, k8=0,1 halves
#define ISSUE_BFV(bfvN, d_, e_, cb_)                                       \
  do {                                                                     \
    int colbase = l15 + (e_);                                              \
    int base0 = ((wn + (d_)) * 66 + colbase) * 512 + (cb_)*128;            \
    int s0 = ((l4) ^ (colbase & 7)) * 16;                                  \
    int s1 = ((4 + l4) ^ (colbase & 7)) * 16;                              \
    GLOAD(bfvN[0][0], base0 + s0);                                         \
    GLOAD(bfvN[0][1], base0 + s1);                                         \
    GLOAD(bfvN[1][0], base0 + 8192 + s0);                                  \
    GLOAD(bfvN[1][1], base0 + 8192 + s1);                                  \
    GLOAD(bfvN[2][0], base0 + 16384 + s0);                                 \
    GLOAD(bfvN[2][1], base0 + 16384 + s1);                                 \
    GLOAD(bfvN[3][0], base0 + 24576 + s0);                                 \
    GLOAD(bfvN[3][1], base0 + 24576 + s1);                                 \
  } while (0)

  int d = 0, e = 0, de = 0, cb = 0;

  // one K-step: stage A[s+1], issue bfv[s+1], compute with bfv_cur from A=Acur
  auto step = [&](unsigned short* Acur, unsigned short* Anext, bf16x8 (&bfvC)[4][2],
                  bf16x8 (&bfvN)[4][2]) {
    // next-step tap params
    int nde = de + 1, ncb = cb, nd = d, ne = e + 1;
    if (ne == 3) { ne = 0; nd = d + 1; }
    if (nde == 9) { nde = 0; ncb = cb + 1; nd = 0; ne = 0; }
    int ccb = (ncb > 3) ? 3 : ncb;  // dummy (discarded) loads on the last step

    STAGE_A(Anext, nde, ccb);
    asm volatile("" ::: "memory");  // A-issues strictly before bfv-issues (vmcnt order)
    ISSUE_BFV(bfvN, nd, ne, ccb);

    // retire bfv_cur (oldest 8 of <=20 outstanding); A[s+1]+bfv[s+1] remain in flight
    asm volatile("s_waitcnt vmcnt(12)" ::: "memory");
    __builtin_amdgcn_sched_barrier(0);
    __builtin_amdgcn_s_setprio(1);
#pragma unroll
    for (int k8 = 0; k8 < 2; ++k8) {
      bf16x8 af[8];
#pragma unroll
      for (int i = 0; i < 8; ++i) {
        int row = wm * 128 + i * 16 + l15;
        int slot = (k8 * 4 + l4) ^ (row & 7);
        af[i] = *(const bf16x8*)(Acur + (size_t)row * 64 + slot * 8);
      }
#pragma unroll
      for (int i = 0; i < 8; ++i)
#pragma unroll
        for (int j = 0; j < 4; ++j)
          acc[i][j] = __builtin_amdgcn_mfma_f32_16x16x32_bf16(af[i], bfvC[j][k8],
                                                              acc[i][j], 0, 0, 0);
    }
    __builtin_amdgcn_s_setprio(0);
    // drain A[s+1] (oldest 4 of 12); bfv[s+1] stays in flight across the barrier
    asm volatile("s_waitcnt vmcnt(8)" ::: "memory");
    __builtin_amdgcn_s_barrier();
    asm volatile("" ::: "memory");

    d = nd; e = ne; de = nde; cb = ncb;
  };

  // prologue: A[0] + bfv[0] in flight; drain A[0] only
  STAGE_A(at0, 0, 0);
  asm volatile("" ::: "memory");
  ISSUE_BFV(bfvA, 0, 0, 0);
  asm volatile("s_waitcnt vmcnt(8)" ::: "memory");
  __builtin_amdgcn_s_barrier();
  asm volatile("" ::: "memory");

  for (int sp = 0; sp < 18; ++sp) {
    step(at0, at1, bfvA, bfvB);
    step(at1, at0, bfvB, bfvA);
  }
#undef GLOAD
#undef STAGE_A
#undef ISSUE_BFV

  const float kSqrt2 = 1.41421356237309515f;
  const int oh = 2 * (m0 + wn) + py;
#pragma unroll
  for (int i = 0; i < 8; ++i) {
    const int row0 = wm * 128 + i * 16 + l4 * 4;  // even
    const int co0 = row0 >> 1;                    // r=0,1 -> co0 (px=0,1); r=2,3 -> co0+1
    const float bs0 = bias[co0], bs1 = bias[co0 + 1];
#pragma unroll
    for (int j = 0; j < 4; ++j) {
      const int n = j * 16 + l15;
      float v[4];
#pragma unroll
      for (int r = 0; r < 4; ++r) {
        float vv = acc[i][j][r] + ((r < 2) ? bs0 : bs1);
        vv = (vv < 0.f ? 0.01f * vv : vv) * kSqrt2;
        v[r] = fminf(fmaxf(vv, -256.f), 265.f);
      }
      float2* p0 = (float2*)&out[(((size_t)b * COUT + co0) * 128 + oh) * 128 + 2 * n];
      float2* p1 = (float2*)&out[(((size_t)b * COUT + co0 + 1) * 128 + oh) * 128 + 2 * n];
      *p0 = make_float2(v[0], v[1]);
      *p1 = make_float2(v[2], v[3]);
    }
  }
}

extern "C" void kernel_launch(void* const* d_in, const int* in_sizes, int n_in,
                              void* d_out, int out_size, void* d_ws, size_t ws_size,
                              hipStream_t stream) {
  const float* x = (const float*)d_in[0];
  const float* w = (const float*)d_in[1];
  const float* bias = (const float*)d_in[2];
  const float* f = (const float*)d_in[3];
  float* out = (float*)d_out;

  unsigned short* xb2 = (unsigned short*)d_ws;
  unsigned short* gw3 = (unsigned short*)((char*)d_ws + XB2_BYTES);

  hipMemsetAsync(d_ws, 0, XB2_BYTES, stream);  // zero border of xb2
  hipLaunchKernelGGL(prep_x, dim3(BATCH * HH), dim3(256), 0, stream, x, xb2);
  hipLaunchKernelGGL(prep_w, dim3(128), dim3(256), 0, stream, w, f, gw3);
  hipLaunchKernelGGL(conv_main, dim3(256), dim3(512), 0, stream, xb2, gw3, bias, out);
}